// Round 1
// baseline (428.493 us; speedup 1.0000x reference)
//
#include <hip/hip_runtime.h>

#define IN_C 64
#define OUT_C 64

// -------- Kernel 1: h[n][c] = sum_k x[n][k] * W[k][c] --------
// Block = 256 threads = 4 nodes x 64 channels. W staged in LDS (16 KB),
// x rows staged in LDS (1 KB).
__global__ __launch_bounds__(256) void gcn_gemm_kernel(
    const float* __restrict__ x, const float* __restrict__ w,
    float* __restrict__ h, int n_nodes) {
    __shared__ float wlds[IN_C][OUT_C];   // 16 KB
    __shared__ float xl[4][IN_C];         // 1 KB

    const int tid = threadIdx.x;
    // cooperative load of W: 4096 elems / 256 threads = 16 each, coalesced
    #pragma unroll
    for (int i = tid; i < IN_C * OUT_C; i += 256) {
        wlds[i >> 6][i & 63] = w[i];
    }

    const int local = tid >> 6;                  // wave id in block (0..3)
    const int lane  = tid & 63;                  // channel
    const int node  = blockIdx.x * 4 + local;

    if (node < n_nodes) {
        xl[local][lane] = x[node * IN_C + lane]; // coalesced row load
    }
    __syncthreads();

    if (node >= n_nodes) return;

    float acc = 0.f;
    #pragma unroll
    for (int k = 0; k < IN_C; ++k) {
        // xl[local][k]: same addr across wave -> LDS broadcast (free)
        // wlds[k][lane]: stride-1 across 64 lanes -> 2-way bank alias (free)
        acc += xl[local][k] * wlds[k][lane];
    }
    h[node * OUT_C + lane] = acc;
}

// -------- Kernel 2: segment-sum + degree scale + bias --------
// One wave (64 lanes) per destination node; lane = output channel.
// row_index is sorted, so the wave binary-searches its edge range.
__global__ __launch_bounds__(256) void gcn_agg_kernel(
    const float* __restrict__ h, const int* __restrict__ col_idx,
    const int* __restrict__ row_idx, const float* __restrict__ deg,
    const float* __restrict__ bias, float* __restrict__ out,
    int n_nodes, int n_edges) {
    const int tid  = threadIdx.x;
    const int node = blockIdx.x * 4 + (tid >> 6);
    if (node >= n_nodes) return;
    const int lane = tid & 63;

    // lower_bound(row_idx, node) — uniform across the wave (broadcast loads)
    int lo = 0, hi = n_edges;
    while (lo < hi) {
        int mid = (lo + hi) >> 1;
        if (row_idx[mid] < node) lo = mid + 1; else hi = mid;
    }
    const int begin = lo;
    // lower_bound(row_idx, node+1), starting from begin
    hi = n_edges;
    while (lo < hi) {
        int mid = (lo + hi) >> 1;
        if (row_idx[mid] < node + 1) lo = mid + 1; else hi = mid;
    }
    const int end = lo;

    float acc = 0.f;
    for (int e = begin; e < end; ++e) {
        const int c = col_idx[e];          // uniform across wave (broadcast)
        acc += h[c * OUT_C + lane];        // coalesced 256 B line per edge
    }
    out[node * OUT_C + lane] = acc * deg[node] + bias[lane];
}

extern "C" void kernel_launch(void* const* d_in, const int* in_sizes, int n_in,
                              void* d_out, int out_size, void* d_ws, size_t ws_size,
                              hipStream_t stream) {
    const float* x    = (const float*)d_in[0];
    const float* w    = (const float*)d_in[1];
    const float* bias = (const float*)d_in[2];
    const int* col    = (const int*)d_in[3];
    const int* row    = (const int*)d_in[4];
    const float* deg  = (const float*)d_in[5];
    float* out        = (float*)d_out;
    float* h          = (float*)d_ws;      // 100000*64*4 = 25.6 MB scratch

    const int n_nodes = in_sizes[5];       // degrees: [N_NODES]
    const int n_edges = in_sizes[3];       // column_index: [N_EDGES]

    const int blocks = (n_nodes + 3) / 4;  // 4 nodes per 256-thread block
    gcn_gemm_kernel<<<blocks, 256, 0, stream>>>(x, w, h, n_nodes);
    gcn_agg_kernel<<<blocks, 256, 0, stream>>>(h, col, row, deg, bias, out,
                                               n_nodes, n_edges);
}

// Round 2
// 260.454 us; speedup vs baseline: 1.6452x; 1.6452x over previous
//
#include <hip/hip_runtime.h>

#define IN_C 64
#define OUT_C 64

// -------- Kernel 1: h[n][c] = sum_k x[n][k] * W[k][c] --------
// Grid-stride, one wave per node per iteration. W column held in 64 VGPRs
// per lane (loaded once per wave); x row broadcast via __shfl (readlane).
__global__ __launch_bounds__(256) void gcn_gemm_kernel(
    const float* __restrict__ x, const float* __restrict__ w,
    float* __restrict__ h, int n_nodes) {
    const int lane   = threadIdx.x & 63;
    const int wid    = blockIdx.x * (blockDim.x >> 6) + (threadIdx.x >> 6);
    const int nwaves = gridDim.x * (blockDim.x >> 6);

    // W column for this lane: wcol[k] = W[k][lane]  (coalesced, L2-hot)
    float wcol[IN_C];
    #pragma unroll
    for (int k = 0; k < IN_C; ++k) wcol[k] = w[k * OUT_C + lane];

    for (int n = wid; n < n_nodes; n += nwaves) {
        const float xv = x[(size_t)n * IN_C + lane];   // coalesced row load
        float a0 = 0.f, a1 = 0.f, a2 = 0.f, a3 = 0.f;  // 4 chains for ILP
        #pragma unroll
        for (int k = 0; k < IN_C; k += 4) {
            a0 += __shfl(xv, k + 0) * wcol[k + 0];
            a1 += __shfl(xv, k + 1) * wcol[k + 1];
            a2 += __shfl(xv, k + 2) * wcol[k + 2];
            a3 += __shfl(xv, k + 3) * wcol[k + 3];
        }
        h[(size_t)n * OUT_C + lane] = (a0 + a1) + (a2 + a3);
    }
}

// -------- Kernel 2: build CSR rowptr from sorted row_index --------
// rowptr[n] = first edge e with row[e] >= n; rowptr[N] = E.
__global__ __launch_bounds__(256) void build_rowptr_kernel(
    const int* __restrict__ row, int* __restrict__ rowptr,
    int n_nodes, int n_edges) {
    const int e = blockIdx.x * blockDim.x + threadIdx.x;
    if (e >= n_edges) return;
    const int r     = row[e];
    const int rprev = (e == 0) ? -1 : row[e - 1];
    for (int n = rprev + 1; n <= r; ++n) rowptr[n] = e;
    if (e == n_edges - 1) {
        for (int n = r + 1; n <= n_nodes; ++n) rowptr[n] = n_edges;
    }
}

// -------- Kernel 3: segment-sum + degree scale + bias (rowptr path) ----
// One wave per node, lane = channel. Col indices loaded 64-at-a-time
// (one coalesced load) and broadcast via __shfl, so all h gathers in the
// chunk are independent and pipeline freely.
__global__ __launch_bounds__(256) void gcn_agg_rowptr_kernel(
    const float* __restrict__ h, const int* __restrict__ col_idx,
    const int* __restrict__ rowptr, const float* __restrict__ deg,
    const float* __restrict__ bias, float* __restrict__ out,
    int n_nodes) {
    const int tid  = threadIdx.x;
    const int node = blockIdx.x * 4 + (tid >> 6);
    if (node >= n_nodes) return;
    const int lane = tid & 63;

    const int begin = rowptr[node];
    const int end   = rowptr[node + 1];

    float acc = 0.f;
    for (int base = begin; base < end; base += 64) {
        const int cnt  = min(end - base, 64);
        const int colv = (base + lane < end) ? col_idx[base + lane] : 0;
        for (int i = 0; i < cnt; ++i) {
            const int c = __shfl(colv, i);              // uniform broadcast
            acc += h[(size_t)c * OUT_C + lane];         // coalesced 256 B line
        }
    }
    out[(size_t)node * OUT_C + lane] = acc * deg[node] + bias[lane];
}

// -------- Fallback agg (binary search) if ws too small for rowptr ------
__global__ __launch_bounds__(256) void gcn_agg_bsearch_kernel(
    const float* __restrict__ h, const int* __restrict__ col_idx,
    const int* __restrict__ row_idx, const float* __restrict__ deg,
    const float* __restrict__ bias, float* __restrict__ out,
    int n_nodes, int n_edges) {
    const int tid  = threadIdx.x;
    const int node = blockIdx.x * 4 + (tid >> 6);
    if (node >= n_nodes) return;
    const int lane = tid & 63;

    int lo = 0, hi = n_edges;
    while (lo < hi) {
        int mid = (lo + hi) >> 1;
        if (row_idx[mid] < node) lo = mid + 1; else hi = mid;
    }
    const int begin = lo;
    hi = n_edges;
    while (lo < hi) {
        int mid = (lo + hi) >> 1;
        if (row_idx[mid] < node + 1) lo = mid + 1; else hi = mid;
    }
    const int end = lo;

    float acc = 0.f;
    for (int e = begin; e < end; ++e) {
        acc += h[(size_t)col_idx[e] * OUT_C + lane];
    }
    out[(size_t)node * OUT_C + lane] = acc * deg[node] + bias[lane];
}

extern "C" void kernel_launch(void* const* d_in, const int* in_sizes, int n_in,
                              void* d_out, int out_size, void* d_ws, size_t ws_size,
                              hipStream_t stream) {
    const float* x    = (const float*)d_in[0];
    const float* w    = (const float*)d_in[1];
    const float* bias = (const float*)d_in[2];
    const int* col    = (const int*)d_in[3];
    const int* row    = (const int*)d_in[4];
    const float* deg  = (const float*)d_in[5];
    float* out        = (float*)d_out;

    const int n_nodes = in_sizes[5];     // degrees: [N_NODES]
    const int n_edges = in_sizes[3];     // column_index: [N_EDGES]

    float* h = (float*)d_ws;             // 25.6 MB
    const size_t h_bytes      = (size_t)n_nodes * OUT_C * sizeof(float);
    const size_t rowptr_bytes = (size_t)(n_nodes + 1) * sizeof(int);
    int* rowptr = (int*)((char*)d_ws + h_bytes);

    // GEMM: 2048 blocks x 4 waves = 8192 waves, ~12 nodes each
    gcn_gemm_kernel<<<2048, 256, 0, stream>>>(x, w, h, n_nodes);

    const int agg_blocks = (n_nodes + 3) / 4;
    if (ws_size >= h_bytes + rowptr_bytes) {
        build_rowptr_kernel<<<(n_edges + 255) / 256, 256, 0, stream>>>(
            row, rowptr, n_nodes, n_edges);
        gcn_agg_rowptr_kernel<<<agg_blocks, 256, 0, stream>>>(
            h, col, rowptr, deg, bias, out, n_nodes);
    } else {
        gcn_agg_bsearch_kernel<<<agg_blocks, 256, 0, stream>>>(
            h, col, row, deg, bias, out, n_nodes, n_edges);
    }
}

// Round 3
// 172.710 us; speedup vs baseline: 2.4810x; 1.5080x over previous
//
#include <hip/hip_runtime.h>

#define IN_C 64
#define OUT_C 64

// -------- Kernel 1 (fused): GEMM h = x@W  +  CSR rowptr build --------
// Blocks [0, gemm_blocks): one wave per node (grid-stride). W column in 64
// VGPRs (loaded once per wave); x row via wave-uniform scalar loads.
// Blocks [gemm_blocks, ...): edge-parallel rowptr fill from sorted row_index.
__global__ __launch_bounds__(256) void gcn_prep_kernel(
    const float* __restrict__ x, const float* __restrict__ w,
    float* __restrict__ h,
    const int* __restrict__ row, int* __restrict__ rowptr,
    int n_nodes, int n_edges, int gemm_blocks) {
    if ((int)blockIdx.x < gemm_blocks) {
        const int lane   = threadIdx.x & 63;
        const int wid    = blockIdx.x * 4 + (threadIdx.x >> 6);
        const int nwaves = gemm_blocks * 4;

        float wcol[IN_C];                        // W[:, lane] in VGPRs
        #pragma unroll
        for (int k = 0; k < IN_C; ++k) wcol[k] = w[k * OUT_C + lane];

        for (int n = wid; n < n_nodes; n += nwaves) {
            const int nu = __builtin_amdgcn_readfirstlane(n); // force uniform
            const float* __restrict__ xrow = x + (size_t)nu * IN_C;
            float a0 = 0.f, a1 = 0.f, a2 = 0.f, a3 = 0.f;
            #pragma unroll
            for (int k = 0; k < IN_C; k += 4) {  // xrow[k] uniform -> s_load
                a0 = fmaf(xrow[k + 0], wcol[k + 0], a0);
                a1 = fmaf(xrow[k + 1], wcol[k + 1], a1);
                a2 = fmaf(xrow[k + 2], wcol[k + 2], a2);
                a3 = fmaf(xrow[k + 3], wcol[k + 3], a3);
            }
            h[(size_t)nu * OUT_C + lane] = (a0 + a1) + (a2 + a3);
        }
    } else {
        const int e = (blockIdx.x - gemm_blocks) * 256 + threadIdx.x;
        if (e >= n_edges) return;
        const int r     = row[e];
        const int rprev = (e == 0) ? -1 : row[e - 1];
        for (int n = rprev + 1; n <= r; ++n) rowptr[n] = e;
        if (e == n_edges - 1) {
            for (int n = r + 1; n <= n_nodes; ++n) rowptr[n] = n_edges;
        }
    }
}

// -------- Kernel 2: segment-sum + degree scale + bias --------
// One wave per node. Lane split: hi = lane>>4 (edge slot), lo = lane&15
// (float4 channel group). 16 edges per iteration, 4 independent
// global_load_dwordx4 in flight per wave. 2-step shfl_xor reduce at end.
__global__ __launch_bounds__(256) void gcn_agg_kernel(
    const float4* __restrict__ h4, const int* __restrict__ col,
    const int* __restrict__ rowptr, const float* __restrict__ deg,
    const float4* __restrict__ bias4, float4* __restrict__ out4,
    int n_nodes) {
    const int tid  = threadIdx.x;
    const int node = blockIdx.x * 4 + (tid >> 6);
    if (node >= n_nodes) return;
    const int lane = tid & 63;
    const int hi   = lane >> 4;
    const int lo   = lane & 15;

    const int begin = rowptr[node];
    const int end   = rowptr[node + 1];

    float4 acc = make_float4(0.f, 0.f, 0.f, 0.f);
    if (begin < end) {
        const int last = end - 1;
        for (int base = begin; base < end; base += 16) {
            const int e0 = base + hi;
            const int e1 = base + 4 + hi;
            const int e2 = base + 8 + hi;
            const int e3 = base + 12 + hi;
            // clamped loads: always in-range, predicated accumulate below
            const int c0 = col[min(e0, last)];
            const int c1 = col[min(e1, last)];
            const int c2 = col[min(e2, last)];
            const int c3 = col[min(e3, last)];
            const float4 v0 = h4[(size_t)c0 * 16 + lo];
            const float4 v1 = h4[(size_t)c1 * 16 + lo];
            const float4 v2 = h4[(size_t)c2 * 16 + lo];
            const float4 v3 = h4[(size_t)c3 * 16 + lo];
            if (e0 <= last) { acc.x += v0.x; acc.y += v0.y; acc.z += v0.z; acc.w += v0.w; }
            if (e1 <= last) { acc.x += v1.x; acc.y += v1.y; acc.z += v1.z; acc.w += v1.w; }
            if (e2 <= last) { acc.x += v2.x; acc.y += v2.y; acc.z += v2.z; acc.w += v2.w; }
            if (e3 <= last) { acc.x += v3.x; acc.y += v3.y; acc.z += v3.z; acc.w += v3.w; }
        }
        // sum the 4 edge-slot partials (lanes differing in bits 4..5)
        #pragma unroll
        for (int m = 16; m < 64; m <<= 1) {
            acc.x += __shfl_xor(acc.x, m);
            acc.y += __shfl_xor(acc.y, m);
            acc.z += __shfl_xor(acc.z, m);
            acc.w += __shfl_xor(acc.w, m);
        }
    }
    if (hi == 0) {
        const float  d = deg[node];
        const float4 b = bias4[lo];
        float4 o;
        o.x = fmaf(acc.x, d, b.x);
        o.y = fmaf(acc.y, d, b.y);
        o.z = fmaf(acc.z, d, b.z);
        o.w = fmaf(acc.w, d, b.w);
        out4[(size_t)node * (OUT_C / 4) + lo] = o;
    }
}

extern "C" void kernel_launch(void* const* d_in, const int* in_sizes, int n_in,
                              void* d_out, int out_size, void* d_ws, size_t ws_size,
                              hipStream_t stream) {
    const float* x    = (const float*)d_in[0];
    const float* w    = (const float*)d_in[1];
    const float* bias = (const float*)d_in[2];
    const int* col    = (const int*)d_in[3];
    const int* row    = (const int*)d_in[4];
    const float* deg  = (const float*)d_in[5];

    const int n_nodes = in_sizes[5];     // degrees: [N_NODES]
    const int n_edges = in_sizes[3];     // column_index: [N_EDGES]

    float* h    = (float*)d_ws;                           // N*64 f32
    int* rowptr = (int*)((char*)d_ws +
                         (size_t)n_nodes * OUT_C * sizeof(float)); // N+1 ints

    const int gemm_blocks   = 2048;                 // 8192 waves, ~12 nodes ea
    const int rowptr_blocks = (n_edges + 255) / 256;
    gcn_prep_kernel<<<gemm_blocks + rowptr_blocks, 256, 0, stream>>>(
        x, w, h, row, rowptr, n_nodes, n_edges, gemm_blocks);

    const int agg_blocks = (n_nodes + 3) / 4;
    gcn_agg_kernel<<<agg_blocks, 256, 0, stream>>>(
        (const float4*)h, col, rowptr, deg,
        (const float4*)bias, (float4*)d_out, n_nodes);
}

// Round 4
// 159.006 us; speedup vs baseline: 2.6948x; 1.0862x over previous
//
#include <hip/hip_runtime.h>
#include <hip/hip_bf16.h>

#define IN_C 64
#define OUT_C 64
#define NPB 64   // nodes per block in the GEMM half

// -------- Kernel 1 (fused): GEMM h = bf16(x@W)  +  CSR rowptr build -----
// Blocks [0, gemm_blocks): 64 nodes/block. W column in 64 VGPRs per lane;
// x tile staged in LDS via coalesced float4, read back as broadcast
// ds_read_b128 (wave-uniform address). h stored as bf16 (RNE).
// Blocks [gemm_blocks, ...): edge-parallel rowptr fill from sorted row_index.
__global__ __launch_bounds__(256) void gcn_prep_kernel(
    const float* __restrict__ x, const float* __restrict__ w,
    __hip_bfloat16* __restrict__ h,
    const int* __restrict__ row, int* __restrict__ rowptr,
    int n_nodes, int n_edges, int gemm_blocks) {
    if ((int)blockIdx.x < gemm_blocks) {
        __shared__ float xl[NPB][IN_C];      // 16 KB
        const int tid   = threadIdx.x;
        const int lane  = tid & 63;
        const int wv    = tid >> 6;
        const int node0 = blockIdx.x * NPB;
        const int nvalid = min(NPB, n_nodes - node0);

        // W[:, lane] into VGPRs (64 coalesced dword loads, L2-hot)
        float wcol[IN_C];
        #pragma unroll
        for (int k = 0; k < IN_C; ++k) wcol[k] = w[k * OUT_C + lane];

        // stage x tile: 64 nodes x 16 float4, 4 float4 per thread, coalesced
        const float4* x4 = (const float4*)(x + (size_t)node0 * IN_C);
        float4* xl4 = (float4*)&xl[0][0];
        #pragma unroll
        for (int i = tid; i < NPB * (IN_C / 4); i += 256) {
            const int n = i >> 4;
            float4 v = make_float4(0.f, 0.f, 0.f, 0.f);
            if (n < nvalid) v = x4[i];
            xl4[i] = v;
        }
        __syncthreads();

        // each wave computes 16 nodes; xl[n][k..k+3] is a broadcast b128 read
        for (int j = 0; j < 16; ++j) {
            const int n = wv * 16 + j;
            if (n >= nvalid) break;
            float a0 = 0.f, a1 = 0.f, a2 = 0.f, a3 = 0.f;
            #pragma unroll
            for (int k = 0; k < IN_C; k += 4) {
                a0 = fmaf(xl[n][k + 0], wcol[k + 0], a0);
                a1 = fmaf(xl[n][k + 1], wcol[k + 1], a1);
                a2 = fmaf(xl[n][k + 2], wcol[k + 2], a2);
                a3 = fmaf(xl[n][k + 3], wcol[k + 3], a3);
            }
            h[(size_t)(node0 + n) * OUT_C + lane] =
                __float2bfloat16((a0 + a1) + (a2 + a3));
        }
    } else {
        const int e = (blockIdx.x - gemm_blocks) * 256 + threadIdx.x;
        if (e >= n_edges) return;
        const int r     = row[e];
        const int rprev = (e == 0) ? -1 : row[e - 1];
        for (int n = rprev + 1; n <= r; ++n) rowptr[n] = e;
        if (e == n_edges - 1) {
            for (int n = r + 1; n <= n_nodes; ++n) rowptr[n] = n_edges;
        }
    }
}

// -------- Kernel 2: bf16 segment-sum + degree scale + bias --------
// One wave per node. Lane split: hi = lane>>3 (8 edge slots), lo = lane&7
// (8 bf16 channels = one uint4 = 16 B). 16 edges/iter, 2 independent 16 B
// loads per lane. fp32 accumulate, 3-step shfl_xor reduce over edge slots.
__global__ __launch_bounds__(256) void gcn_agg_kernel(
    const uint4* __restrict__ h4, const int* __restrict__ col,
    const int* __restrict__ rowptr, const float* __restrict__ deg,
    const float4* __restrict__ bias4, float4* __restrict__ out4,
    int n_nodes) {
    const int tid  = threadIdx.x;
    const int node = blockIdx.x * 4 + (tid >> 6);
    if (node >= n_nodes) return;
    const int lane = tid & 63;
    const int hi   = lane >> 3;
    const int lo   = lane & 7;

    const int begin = rowptr[node];
    const int end   = rowptr[node + 1];

    float acc[8] = {0.f, 0.f, 0.f, 0.f, 0.f, 0.f, 0.f, 0.f};
    if (begin < end) {
        const int last = end - 1;
        for (int base = begin; base < end; base += 16) {
            const int e0 = base + hi;
            const int e1 = base + 8 + hi;
            const int c0 = col[min(e0, last)];
            const int c1 = col[min(e1, last)];
            const uint4 v0 = h4[(size_t)c0 * 8 + lo];
            const uint4 v1 = h4[(size_t)c1 * 8 + lo];
            if (e0 <= last) {
                acc[0] += __uint_as_float(v0.x << 16);
                acc[1] += __uint_as_float(v0.x & 0xFFFF0000u);
                acc[2] += __uint_as_float(v0.y << 16);
                acc[3] += __uint_as_float(v0.y & 0xFFFF0000u);
                acc[4] += __uint_as_float(v0.z << 16);
                acc[5] += __uint_as_float(v0.z & 0xFFFF0000u);
                acc[6] += __uint_as_float(v0.w << 16);
                acc[7] += __uint_as_float(v0.w & 0xFFFF0000u);
            }
            if (e1 <= last) {
                acc[0] += __uint_as_float(v1.x << 16);
                acc[1] += __uint_as_float(v1.x & 0xFFFF0000u);
                acc[2] += __uint_as_float(v1.y << 16);
                acc[3] += __uint_as_float(v1.y & 0xFFFF0000u);
                acc[4] += __uint_as_float(v1.z << 16);
                acc[5] += __uint_as_float(v1.z & 0xFFFF0000u);
                acc[6] += __uint_as_float(v1.w << 16);
                acc[7] += __uint_as_float(v1.w & 0xFFFF0000u);
            }
        }
        #pragma unroll
        for (int m = 8; m < 64; m <<= 1) {
            #pragma unroll
            for (int i = 0; i < 8; ++i) acc[i] += __shfl_xor(acc[i], m);
        }
    }
    if (hi == 0) {
        const float  d  = deg[node];
        const float4 b0 = bias4[lo * 2];
        const float4 b1 = bias4[lo * 2 + 1];
        float4 oa, ob;
        oa.x = fmaf(acc[0], d, b0.x);
        oa.y = fmaf(acc[1], d, b0.y);
        oa.z = fmaf(acc[2], d, b0.z);
        oa.w = fmaf(acc[3], d, b0.w);
        ob.x = fmaf(acc[4], d, b1.x);
        ob.y = fmaf(acc[5], d, b1.y);
        ob.z = fmaf(acc[6], d, b1.z);
        ob.w = fmaf(acc[7], d, b1.w);
        out4[(size_t)node * 16 + lo * 2]     = oa;
        out4[(size_t)node * 16 + lo * 2 + 1] = ob;
    }
}

extern "C" void kernel_launch(void* const* d_in, const int* in_sizes, int n_in,
                              void* d_out, int out_size, void* d_ws, size_t ws_size,
                              hipStream_t stream) {
    const float* x    = (const float*)d_in[0];
    const float* w    = (const float*)d_in[1];
    const float* bias = (const float*)d_in[2];
    const int* col    = (const int*)d_in[3];
    const int* row    = (const int*)d_in[4];
    const float* deg  = (const float*)d_in[5];

    const int n_nodes = in_sizes[5];     // degrees: [N_NODES]
    const int n_edges = in_sizes[3];     // column_index: [N_EDGES]

    __hip_bfloat16* h = (__hip_bfloat16*)d_ws;            // N*64 bf16 = 12.8 MB
    int* rowptr = (int*)((char*)d_ws +
                         (size_t)n_nodes * OUT_C * sizeof(__hip_bfloat16));

    const int gemm_blocks   = (n_nodes + NPB - 1) / NPB;  // 1563
    const int rowptr_blocks = (n_edges + 255) / 256;      // 6250
    gcn_prep_kernel<<<gemm_blocks + rowptr_blocks, 256, 0, stream>>>(
        x, w, h, row, rowptr, n_nodes, n_edges, gemm_blocks);

    const int agg_blocks = (n_nodes + 3) / 4;
    gcn_agg_kernel<<<agg_blocks, 256, 0, stream>>>(
        (const uint4*)h, col, rowptr, deg,
        (const float4*)bias, (float4*)d_out, n_nodes);
}

// Round 6
// 149.900 us; speedup vs baseline: 2.8585x; 1.0607x over previous
//
#include <hip/hip_runtime.h>
#include <hip/hip_bf16.h>

#define IN_C 64
#define OUT_C 64
#define NPB 64   // nodes per block in the GEMM half

// -------- Kernel 1 (fused): GEMM h = bf16(x@W)  +  CSR rowptr build -----
// Blocks [0, gemm_blocks): 64 nodes/block. W column in 64 VGPRs per lane;
// x tile staged in LDS via coalesced float4, read back as broadcast
// ds_read_b128 (wave-uniform address). h stored as bf16 (RNE).
// Blocks [gemm_blocks, ...): edge-parallel rowptr fill from sorted row_index.
__global__ __launch_bounds__(256) void gcn_prep_kernel(
    const float* __restrict__ x, const float* __restrict__ w,
    __hip_bfloat16* __restrict__ h,
    const int* __restrict__ row, int* __restrict__ rowptr,
    int n_nodes, int n_edges, int gemm_blocks) {
    if ((int)blockIdx.x < gemm_blocks) {
        __shared__ float xl[NPB][IN_C];      // 16 KB
        const int tid   = threadIdx.x;
        const int lane  = tid & 63;
        const int wv    = tid >> 6;
        const int node0 = blockIdx.x * NPB;
        const int nvalid = min(NPB, n_nodes - node0);

        // W[:, lane] into VGPRs (64 coalesced dword loads, L2-hot)
        float wcol[IN_C];
        #pragma unroll
        for (int k = 0; k < IN_C; ++k) wcol[k] = w[k * OUT_C + lane];

        // stage x tile: 64 nodes x 16 float4, 4 float4 per thread, coalesced
        const float4* x4 = (const float4*)(x + (size_t)node0 * IN_C);
        float4* xl4 = (float4*)&xl[0][0];
        #pragma unroll
        for (int i = tid; i < NPB * (IN_C / 4); i += 256) {
            const int n = i >> 4;
            float4 v = make_float4(0.f, 0.f, 0.f, 0.f);
            if (n < nvalid) v = x4[i];
            xl4[i] = v;
        }
        __syncthreads();

        // each wave computes 16 nodes; xl[n][k..k+3] is a broadcast b128 read
        for (int j = 0; j < 16; ++j) {
            const int n = wv * 16 + j;
            if (n >= nvalid) break;
            float a0 = 0.f, a1 = 0.f, a2 = 0.f, a3 = 0.f;
            #pragma unroll
            for (int k = 0; k < IN_C; k += 4) {
                a0 = fmaf(xl[n][k + 0], wcol[k + 0], a0);
                a1 = fmaf(xl[n][k + 1], wcol[k + 1], a1);
                a2 = fmaf(xl[n][k + 2], wcol[k + 2], a2);
                a3 = fmaf(xl[n][k + 3], wcol[k + 3], a3);
            }
            h[(size_t)(node0 + n) * OUT_C + lane] =
                __float2bfloat16((a0 + a1) + (a2 + a3));
        }
    } else {
        const int e = (blockIdx.x - gemm_blocks) * 256 + threadIdx.x;
        if (e >= n_edges) return;
        const int r     = row[e];
        const int rprev = (e == 0) ? -1 : row[e - 1];
        for (int n = rprev + 1; n <= r; ++n) rowptr[n] = e;
        if (e == n_edges - 1) {
            for (int n = r + 1; n <= n_nodes; ++n) rowptr[n] = n_edges;
        }
    }
}

// -------- Kernel 2: bf16 segment-sum + degree scale + bias --------
// 8 lanes per node (lane owns 8 bf16 channels = one uint4 of the h row),
// 8 nodes per wave, 32 nodes per 256-thread block. No cross-lane reduce:
// each lane accumulates its own channels in fp32 and writes two float4.
// Unroll-4 with clamped edge indices keeps 8 gather loads in flight.
#define UNPACK_ADD(v)                                   \
    do {                                                \
        acc[0] += __uint_as_float((v).x << 16);         \
        acc[1] += __uint_as_float((v).x & 0xFFFF0000u); \
        acc[2] += __uint_as_float((v).y << 16);         \
        acc[3] += __uint_as_float((v).y & 0xFFFF0000u); \
        acc[4] += __uint_as_float((v).z << 16);         \
        acc[5] += __uint_as_float((v).z & 0xFFFF0000u); \
        acc[6] += __uint_as_float((v).w << 16);         \
        acc[7] += __uint_as_float((v).w & 0xFFFF0000u); \
    } while (0)

__global__ __launch_bounds__(256) void gcn_agg_kernel(
    const uint4* __restrict__ h4, const int* __restrict__ col,
    const int* __restrict__ rowptr, const float* __restrict__ deg,
    const float4* __restrict__ bias4, float4* __restrict__ out4,
    int n_nodes) {
    const int tid  = threadIdx.x;
    const int node = blockIdx.x * 32 + (tid >> 3);   // 8 lanes per node
    if (node >= n_nodes) return;
    const int lo   = tid & 7;                        // channel octet

    const int begin = rowptr[node];
    const int end   = rowptr[node + 1];
    const int last  = end - 1;

    float acc[8] = {0.f, 0.f, 0.f, 0.f, 0.f, 0.f, 0.f, 0.f};
    for (int e = begin; e < end; e += 4) {
        const int c0 = col[e];
        const int c1 = col[min(e + 1, last)];
        const int c2 = col[min(e + 2, last)];
        const int c3 = col[min(e + 3, last)];
        const uint4 v0 = h4[(size_t)c0 * 8 + lo];
        const uint4 v1 = h4[(size_t)c1 * 8 + lo];
        const uint4 v2 = h4[(size_t)c2 * 8 + lo];
        const uint4 v3 = h4[(size_t)c3 * 8 + lo];
        UNPACK_ADD(v0);
        if (e + 1 <= last) UNPACK_ADD(v1);
        if (e + 2 <= last) UNPACK_ADD(v2);
        if (e + 3 <= last) UNPACK_ADD(v3);
    }

    const float  d  = deg[node];
    const float4 b0 = bias4[lo * 2];
    const float4 b1 = bias4[lo * 2 + 1];
    float4 oa, ob;
    oa.x = fmaf(acc[0], d, b0.x);
    oa.y = fmaf(acc[1], d, b0.y);
    oa.z = fmaf(acc[2], d, b0.z);
    oa.w = fmaf(acc[3], d, b0.w);
    ob.x = fmaf(acc[4], d, b1.x);
    ob.y = fmaf(acc[5], d, b1.y);
    ob.z = fmaf(acc[6], d, b1.z);
    ob.w = fmaf(acc[7], d, b1.w);
    out4[(size_t)node * 16 + lo * 2]     = oa;
    out4[(size_t)node * 16 + lo * 2 + 1] = ob;
}

extern "C" void kernel_launch(void* const* d_in, const int* in_sizes, int n_in,
                              void* d_out, int out_size, void* d_ws, size_t ws_size,
                              hipStream_t stream) {
    const float* x    = (const float*)d_in[0];
    const float* w    = (const float*)d_in[1];
    const float* bias = (const float*)d_in[2];
    const int* col    = (const int*)d_in[3];
    const int* row    = (const int*)d_in[4];
    const float* deg  = (const float*)d_in[5];

    const int n_nodes = in_sizes[5];     // degrees: [N_NODES]
    const int n_edges = in_sizes[3];     // column_index: [N_EDGES]

    __hip_bfloat16* h = (__hip_bfloat16*)d_ws;            // N*64 bf16 = 12.8 MB
    int* rowptr = (int*)((char*)d_ws +
                         (size_t)n_nodes * OUT_C * sizeof(__hip_bfloat16));

    const int gemm_blocks   = (n_nodes + NPB - 1) / NPB;  // 1563
    const int rowptr_blocks = (n_edges + 255) / 256;      // 6250
    gcn_prep_kernel<<<gemm_blocks + rowptr_blocks, 256, 0, stream>>>(
        x, w, h, row, rowptr, n_nodes, n_edges, gemm_blocks);

    const int agg_blocks = (n_nodes + 31) / 32;           // 32 nodes per block
    gcn_agg_kernel<<<agg_blocks, 256, 0, stream>>>(
        (const uint4*)h, col, rowptr, deg,
        (const float4*)bias, (float4*)d_out, n_nodes);
}

// Round 7
// 146.138 us; speedup vs baseline: 2.9321x; 1.0257x over previous
//
#include <hip/hip_runtime.h>
#include <hip/hip_bf16.h>

#define IN_C 64
#define OUT_C 64
#define NPB 64   // nodes per block in the GEMM half

// -------- Kernel 1 (fused): GEMM h = bf16(x@W)  +  CSR rowptr build -----
// Blocks [0, gemm_blocks): 64 nodes/block. W column in 64 VGPRs per lane;
// x tile staged in LDS via coalesced float4, read back as broadcast
// ds_read_b128 (wave-uniform address). h stored as bf16 (RNE).
// Blocks [gemm_blocks, ...): edge-parallel rowptr fill from sorted row_index.
__global__ __launch_bounds__(256) void gcn_prep_kernel(
    const float* __restrict__ x, const float* __restrict__ w,
    __hip_bfloat16* __restrict__ h,
    const int* __restrict__ row, int* __restrict__ rowptr,
    int n_nodes, int n_edges, int gemm_blocks) {
    if ((int)blockIdx.x < gemm_blocks) {
        __shared__ float xl[NPB][IN_C];      // 16 KB
        const int tid   = threadIdx.x;
        const int lane  = tid & 63;
        const int wv    = tid >> 6;
        const int node0 = blockIdx.x * NPB;
        const int nvalid = min(NPB, n_nodes - node0);

        // W[:, lane] into VGPRs (64 coalesced dword loads, L2-hot)
        float wcol[IN_C];
        #pragma unroll
        for (int k = 0; k < IN_C; ++k) wcol[k] = w[k * OUT_C + lane];

        // stage x tile: 64 nodes x 16 float4, 4 float4 per thread, coalesced
        const float4* x4 = (const float4*)(x + (size_t)node0 * IN_C);
        float4* xl4 = (float4*)&xl[0][0];
        #pragma unroll
        for (int i = tid; i < NPB * (IN_C / 4); i += 256) {
            const int n = i >> 4;
            float4 v = make_float4(0.f, 0.f, 0.f, 0.f);
            if (n < nvalid) v = x4[i];
            xl4[i] = v;
        }
        __syncthreads();

        // each wave computes 16 nodes; xl[n][k..k+3] is a broadcast b128 read
        for (int j = 0; j < 16; ++j) {
            const int n = wv * 16 + j;
            if (n >= nvalid) break;
            float a0 = 0.f, a1 = 0.f, a2 = 0.f, a3 = 0.f;
            #pragma unroll
            for (int k = 0; k < IN_C; k += 4) {
                a0 = fmaf(xl[n][k + 0], wcol[k + 0], a0);
                a1 = fmaf(xl[n][k + 1], wcol[k + 1], a1);
                a2 = fmaf(xl[n][k + 2], wcol[k + 2], a2);
                a3 = fmaf(xl[n][k + 3], wcol[k + 3], a3);
            }
            h[(size_t)(node0 + n) * OUT_C + lane] =
                __float2bfloat16((a0 + a1) + (a2 + a3));
        }
    } else {
        const int e = (blockIdx.x - gemm_blocks) * 256 + threadIdx.x;
        if (e >= n_edges) return;
        const int r     = row[e];
        const int rprev = (e == 0) ? -1 : row[e - 1];
        for (int n = rprev + 1; n <= r; ++n) rowptr[n] = e;
        if (e == n_edges - 1) {
            for (int n = r + 1; n <= n_nodes; ++n) rowptr[n] = n_edges;
        }
    }
}

// -------- Kernel 2: bf16 segment-sum + degree scale + bias --------
// 8 lanes per node (lane owns 8 bf16 channels = one uint4 of the h row),
// 8 nodes per wave, 32 nodes per 256-thread block. No cross-lane reduce.
// Unroll-8 with clamped edge indices: 8 independent col loads then 8
// independent 16 B gathers in flight per lane (deg~16 -> 2 iterations).
#define UNPACK_ADD(v)                                   \
    do {                                                \
        acc[0] += __uint_as_float((v).x << 16);         \
        acc[1] += __uint_as_float((v).x & 0xFFFF0000u); \
        acc[2] += __uint_as_float((v).y << 16);         \
        acc[3] += __uint_as_float((v).y & 0xFFFF0000u); \
        acc[4] += __uint_as_float((v).z << 16);         \
        acc[5] += __uint_as_float((v).z & 0xFFFF0000u); \
        acc[6] += __uint_as_float((v).w << 16);         \
        acc[7] += __uint_as_float((v).w & 0xFFFF0000u); \
    } while (0)

__global__ __launch_bounds__(256) void gcn_agg_kernel(
    const uint4* __restrict__ h4, const int* __restrict__ col,
    const int* __restrict__ rowptr, const float* __restrict__ deg,
    const float4* __restrict__ bias4, float4* __restrict__ out4,
    int n_nodes) {
    const int tid  = threadIdx.x;
    const int node = blockIdx.x * 32 + (tid >> 3);   // 8 lanes per node
    if (node >= n_nodes) return;
    const int lo   = tid & 7;                        // channel octet

    const int begin = rowptr[node];
    const int end   = rowptr[node + 1];
    const int last  = end - 1;

    float acc[8] = {0.f, 0.f, 0.f, 0.f, 0.f, 0.f, 0.f, 0.f};
    for (int e = begin; e < end; e += 8) {
        int c[8];
        #pragma unroll
        for (int i = 0; i < 8; ++i) c[i] = col[min(e + i, last)];
        uint4 v[8];
        #pragma unroll
        for (int i = 0; i < 8; ++i) v[i] = h4[(size_t)c[i] * 8 + lo];
        UNPACK_ADD(v[0]);
        #pragma unroll
        for (int i = 1; i < 8; ++i) {
            if (e + i <= last) UNPACK_ADD(v[i]);
        }
    }

    const float  d  = deg[node];
    const float4 b0 = bias4[lo * 2];
    const float4 b1 = bias4[lo * 2 + 1];
    float4 oa, ob;
    oa.x = fmaf(acc[0], d, b0.x);
    oa.y = fmaf(acc[1], d, b0.y);
    oa.z = fmaf(acc[2], d, b0.z);
    oa.w = fmaf(acc[3], d, b0.w);
    ob.x = fmaf(acc[4], d, b1.x);
    ob.y = fmaf(acc[5], d, b1.y);
    ob.z = fmaf(acc[6], d, b1.z);
    ob.w = fmaf(acc[7], d, b1.w);
    out4[(size_t)node * 16 + lo * 2]     = oa;
    out4[(size_t)node * 16 + lo * 2 + 1] = ob;
}

extern "C" void kernel_launch(void* const* d_in, const int* in_sizes, int n_in,
                              void* d_out, int out_size, void* d_ws, size_t ws_size,
                              hipStream_t stream) {
    const float* x    = (const float*)d_in[0];
    const float* w    = (const float*)d_in[1];
    const float* bias = (const float*)d_in[2];
    const int* col    = (const int*)d_in[3];
    const int* row    = (const int*)d_in[4];
    const float* deg  = (const float*)d_in[5];

    const int n_nodes = in_sizes[5];     // degrees: [N_NODES]
    const int n_edges = in_sizes[3];     // column_index: [N_EDGES]

    __hip_bfloat16* h = (__hip_bfloat16*)d_ws;            // N*64 bf16 = 12.8 MB
    int* rowptr = (int*)((char*)d_ws +
                         (size_t)n_nodes * OUT_C * sizeof(__hip_bfloat16));

    const int gemm_blocks   = (n_nodes + NPB - 1) / NPB;  // 1563
    const int rowptr_blocks = (n_edges + 255) / 256;      // 6250
    gcn_prep_kernel<<<gemm_blocks + rowptr_blocks, 256, 0, stream>>>(
        x, w, h, row, rowptr, n_nodes, n_edges, gemm_blocks);

    const int agg_blocks = (n_nodes + 31) / 32;           // 32 nodes per block
    gcn_agg_kernel<<<agg_blocks, 256, 0, stream>>>(
        (const uint4*)h, col, rowptr, deg,
        (const float4*)bias, (float4*)d_out, n_nodes);
}

// Round 8
// 127.795 us; speedup vs baseline: 3.3530x; 1.1435x over previous
//
#include <hip/hip_runtime.h>
#include <hip/hip_bf16.h>

#define IN_C 64
#define OUT_C 64

typedef __attribute__((ext_vector_type(8))) short bf16x8;
typedef __attribute__((ext_vector_type(4))) float f32x4;

// fp32 -> bf16 (RNE), bit-level, finite inputs
__device__ __forceinline__ short f2bf(float f) {
    unsigned u = __float_as_uint(f);
    unsigned r = (u + 0x7FFFu + ((u >> 16) & 1u)) >> 16;
    return (short)r;
}

// -------- Kernel 1 (fused): MFMA GEMM h = bf16(x@W) + CSR rowptr build ---
// Blocks [0, gemm_blocks): 4 waves/block, each wave = one 16-node M-tile.
//   B (W, 64x64) held as 8 bf16x8 frags (32 VGPRs), loaded from L2 per wave.
//   A (x-tile 16x64) loaded as 2 float4/lane per k-slice, converted to bf16.
//   8x mfma_f32_16x16x32_bf16; C layout: col=lane&15, row=(lane>>4)*4+reg
//   (m89-verified). A/B use the SAME (group,elem)->k map, so the hardware's
//   internal k-permutation cancels.
// Blocks [gemm_blocks, ...): edge-parallel rowptr fill from sorted row_index.
__global__ __launch_bounds__(256) void gcn_prep_kernel(
    const float* __restrict__ x, const float* __restrict__ w,
    unsigned short* __restrict__ h,
    const int* __restrict__ row, int* __restrict__ rowptr,
    int n_nodes, int n_edges, int gemm_blocks) {
    if ((int)blockIdx.x < gemm_blocks) {
        const int lane  = threadIdx.x & 63;
        const int wv    = threadIdx.x >> 6;
        const int m     = lane & 15;   // node-in-tile (A row / C col-lane / B col)
        const int g     = lane >> 4;   // k-group
        const int node0 = ((int)blockIdx.x * 4 + wv) * 16;
        if (node0 >= n_nodes) return;

        // B frags: elem j of frag[ks][nt] = W[ks*32 + g*8 + j][nt*16 + m]
        bf16x8 bfr[2][4];
        #pragma unroll
        for (int ks = 0; ks < 2; ++ks) {
            #pragma unroll
            for (int nt = 0; nt < 4; ++nt) {
                union { short s[8]; bf16x8 v; } u;
                #pragma unroll
                for (int j = 0; j < 8; ++j) {
                    u.s[j] = f2bf(w[(ks * 32 + g * 8 + j) * OUT_C + nt * 16 + m]);
                }
                bfr[ks][nt] = u.v;
            }
        }

        // A frags: elem j of frag[ks] = x[node0+m][ks*32 + g*8 + j]
        const int arow = min(node0 + m, n_nodes - 1);
        const float* xr = x + (size_t)arow * IN_C;
        bf16x8 afr[2];
        #pragma unroll
        for (int ks = 0; ks < 2; ++ks) {
            const float4 p0 = *(const float4*)(xr + ks * 32 + g * 8);
            const float4 p1 = *(const float4*)(xr + ks * 32 + g * 8 + 4);
            union { short s[8]; bf16x8 v; } u;
            u.s[0] = f2bf(p0.x); u.s[1] = f2bf(p0.y);
            u.s[2] = f2bf(p0.z); u.s[3] = f2bf(p0.w);
            u.s[4] = f2bf(p1.x); u.s[5] = f2bf(p1.y);
            u.s[6] = f2bf(p1.z); u.s[7] = f2bf(p1.w);
            afr[ks] = u.v;
        }

        f32x4 acc[4];
        #pragma unroll
        for (int nt = 0; nt < 4; ++nt) acc[nt] = (f32x4){0.f, 0.f, 0.f, 0.f};
        #pragma unroll
        for (int ks = 0; ks < 2; ++ks) {
            #pragma unroll
            for (int nt = 0; nt < 4; ++nt) {
                acc[nt] = __builtin_amdgcn_mfma_f32_16x16x32_bf16(
                    afr[ks], bfr[ks][nt], acc[nt], 0, 0, 0);
            }
        }

        // C store: reg j -> node = node0 + g*4 + j, channel = nt*16 + m
        #pragma unroll
        for (int j = 0; j < 4; ++j) {
            const int node = node0 + g * 4 + j;
            if (node < n_nodes) {
                #pragma unroll
                for (int nt = 0; nt < 4; ++nt) {
                    h[(size_t)node * OUT_C + nt * 16 + m] =
                        (unsigned short)f2bf(acc[nt][j]);
                }
            }
        }
    } else {
        const int e = ((int)blockIdx.x - gemm_blocks) * 256 + threadIdx.x;
        if (e >= n_edges) return;
        const int r     = row[e];
        const int rprev = (e == 0) ? -1 : row[e - 1];
        for (int n = rprev + 1; n <= r; ++n) rowptr[n] = e;
        if (e == n_edges - 1) {
            for (int n = r + 1; n <= n_nodes; ++n) rowptr[n] = n_edges;
        }
    }
}

// -------- Kernel 2: bf16 segment-sum + degree scale + bias --------
// 8 lanes per node (lane owns 8 bf16 channels = one uint4 of the h row),
// 8 nodes per wave, 32 nodes per 256-thread block. No cross-lane reduce.
// Unroll-8 with clamped edge indices: 8 independent col loads then 8
// independent 16 B gathers in flight per lane (deg~16 -> 2 iterations).
#define UNPACK_ADD(v)                                   \
    do {                                                \
        acc[0] += __uint_as_float((v).x << 16);         \
        acc[1] += __uint_as_float((v).x & 0xFFFF0000u); \
        acc[2] += __uint_as_float((v).y << 16);         \
        acc[3] += __uint_as_float((v).y & 0xFFFF0000u); \
        acc[4] += __uint_as_float((v).z << 16);         \
        acc[5] += __uint_as_float((v).z & 0xFFFF0000u); \
        acc[6] += __uint_as_float((v).w << 16);         \
        acc[7] += __uint_as_float((v).w & 0xFFFF0000u); \
    } while (0)

__global__ __launch_bounds__(256) void gcn_agg_kernel(
    const uint4* __restrict__ h4, const int* __restrict__ col,
    const int* __restrict__ rowptr, const float* __restrict__ deg,
    const float4* __restrict__ bias4, float4* __restrict__ out4,
    int n_nodes) {
    const int tid  = threadIdx.x;
    const int node = blockIdx.x * 32 + (tid >> 3);   // 8 lanes per node
    if (node >= n_nodes) return;
    const int lo   = tid & 7;                        // channel octet

    const int begin = rowptr[node];
    const int end   = rowptr[node + 1];
    const int last  = end - 1;

    float acc[8] = {0.f, 0.f, 0.f, 0.f, 0.f, 0.f, 0.f, 0.f};
    for (int e = begin; e < end; e += 8) {
        int c[8];
        #pragma unroll
        for (int i = 0; i < 8; ++i) c[i] = col[min(e + i, last)];
        uint4 v[8];
        #pragma unroll
        for (int i = 0; i < 8; ++i) v[i] = h4[(size_t)c[i] * 8 + lo];
        UNPACK_ADD(v[0]);
        #pragma unroll
        for (int i = 1; i < 8; ++i) {
            if (e + i <= last) UNPACK_ADD(v[i]);
        }
    }

    const float  d  = deg[node];
    const float4 b0 = bias4[lo * 2];
    const float4 b1 = bias4[lo * 2 + 1];
    float4 oa, ob;
    oa.x = fmaf(acc[0], d, b0.x);
    oa.y = fmaf(acc[1], d, b0.y);
    oa.z = fmaf(acc[2], d, b0.z);
    oa.w = fmaf(acc[3], d, b0.w);
    ob.x = fmaf(acc[4], d, b1.x);
    ob.y = fmaf(acc[5], d, b1.y);
    ob.z = fmaf(acc[6], d, b1.z);
    ob.w = fmaf(acc[7], d, b1.w);
    out4[(size_t)node * 16 + lo * 2]     = oa;
    out4[(size_t)node * 16 + lo * 2 + 1] = ob;
}

extern "C" void kernel_launch(void* const* d_in, const int* in_sizes, int n_in,
                              void* d_out, int out_size, void* d_ws, size_t ws_size,
                              hipStream_t stream) {
    const float* x    = (const float*)d_in[0];
    const float* w    = (const float*)d_in[1];
    const float* bias = (const float*)d_in[2];
    const int* col    = (const int*)d_in[3];
    const int* row    = (const int*)d_in[4];
    const float* deg  = (const float*)d_in[5];

    const int n_nodes = in_sizes[5];     // degrees: [N_NODES]
    const int n_edges = in_sizes[3];     // column_index: [N_EDGES]

    unsigned short* h = (unsigned short*)d_ws;            // N*64 bf16 = 12.8 MB
    int* rowptr = (int*)((char*)d_ws +
                         (size_t)n_nodes * OUT_C * sizeof(unsigned short));

    const int gemm_blocks   = (n_nodes + 63) / 64;        // 1563 (64 nodes/blk)
    const int rowptr_blocks = (n_edges + 255) / 256;      // 6250
    gcn_prep_kernel<<<gemm_blocks + rowptr_blocks, 256, 0, stream>>>(
        x, w, h, row, rowptr, n_nodes, n_edges, gemm_blocks);

    const int agg_blocks = (n_nodes + 31) / 32;           // 32 nodes per block
    gcn_agg_kernel<<<agg_blocks, 256, 0, stream>>>(
        (const uint4*)h, col, rowptr, deg,
        (const float4*)bias, (float4*)d_out, n_nodes);
}

// Round 11
// 126.860 us; speedup vs baseline: 3.3777x; 1.0074x over previous
//
#include <hip/hip_runtime.h>
#include <hip/hip_bf16.h>

#define IN_C 64
#define OUT_C 64

typedef __attribute__((ext_vector_type(8))) short bf16x8;
typedef __attribute__((ext_vector_type(4))) float f32x4;

// fp32 -> bf16 (RNE), bit-level, finite inputs
__device__ __forceinline__ short f2bf(float f) {
    unsigned u = __float_as_uint(f);
    unsigned r = (u + 0x7FFFu + ((u >> 16) & 1u)) >> 16;
    return (short)r;
}

// -------- Kernel 1 (fused): MFMA GEMM h = bf16(x@W) + CSR rowptr build ---
// Blocks [0, gemm_blocks): 4 waves/block, each wave = one 16-node M-tile.
//   W staged ONCE per block into LDS in fragment-ready bf16 layout:
//   wlds[(ks*4+nt)*64 + g*16 + m] = {W[ks*32+g*8+j][nt*16+m], j=0..7} (16 B).
//   Per wave: 8 ds_read_b128 for B, 4 float4 loads + 48 cvt for A, 8 MFMA.
//   C layout (m89-verified): col=lane&15, row=(lane>>4)*4+reg.
// Blocks [gemm_blocks, ...): rowptr fill, 4 edges/thread via int4.
__global__ __launch_bounds__(256) void gcn_prep_kernel(
    const float* __restrict__ x, const float* __restrict__ w,
    unsigned short* __restrict__ h,
    const int* __restrict__ row, int* __restrict__ rowptr,
    int n_nodes, int n_edges, int gemm_blocks) {
    if ((int)blockIdx.x < gemm_blocks) {
        __shared__ bf16x8 wlds[512];   // 8 KB, fragment-ready bf16 W
        const int tid  = threadIdx.x;
        const int lane = tid & 63;
        const int wv   = tid >> 6;
        const int m    = lane & 15;    // node-in-tile / B col / C col
        const int g    = lane >> 4;    // k-group

        // cooperative W stage: coalesced global read, fragment-layout LDS write
        #pragma unroll
        for (int i = tid; i < IN_C * OUT_C; i += 256) {
            const int k = i >> 6, c = i & 63;
            const int ks = k >> 5, gg = (k >> 3) & 3, j = k & 7;
            const int nt = c >> 4, mm = c & 15;
            ((short*)wlds)[((ks * 4 + nt) * 64 + gg * 16 + mm) * 8 + j] =
                f2bf(w[i]);
        }
        __syncthreads();

        const int node0 = ((int)blockIdx.x * 4 + wv) * 16;
        if (node0 >= n_nodes) return;

        // B frags from LDS: one ds_read_b128 each
        bf16x8 bfr[2][4];
        #pragma unroll
        for (int ks = 0; ks < 2; ++ks) {
            #pragma unroll
            for (int nt = 0; nt < 4; ++nt) {
                bfr[ks][nt] = wlds[(ks * 4 + nt) * 64 + g * 16 + m];
            }
        }

        // A frags: elem j of frag[ks] = x[node0+m][ks*32 + g*8 + j]
        const int arow = min(node0 + m, n_nodes - 1);
        const float* xr = x + (size_t)arow * IN_C;
        bf16x8 afr[2];
        #pragma unroll
        for (int ks = 0; ks < 2; ++ks) {
            const float4 p0 = *(const float4*)(xr + ks * 32 + g * 8);
            const float4 p1 = *(const float4*)(xr + ks * 32 + g * 8 + 4);
            union { short s[8]; bf16x8 v; } u;
            u.s[0] = f2bf(p0.x); u.s[1] = f2bf(p0.y);
            u.s[2] = f2bf(p0.z); u.s[3] = f2bf(p0.w);
            u.s[4] = f2bf(p1.x); u.s[5] = f2bf(p1.y);
            u.s[6] = f2bf(p1.z); u.s[7] = f2bf(p1.w);
            afr[ks] = u.v;
        }

        f32x4 acc[4];
        #pragma unroll
        for (int nt = 0; nt < 4; ++nt) acc[nt] = (f32x4){0.f, 0.f, 0.f, 0.f};
        #pragma unroll
        for (int ks = 0; ks < 2; ++ks) {
            #pragma unroll
            for (int nt = 0; nt < 4; ++nt) {
                acc[nt] = __builtin_amdgcn_mfma_f32_16x16x32_bf16(
                    afr[ks], bfr[ks][nt], acc[nt], 0, 0, 0);
            }
        }

        // C store: reg j -> node = node0 + g*4 + j, channel = nt*16 + m
        #pragma unroll
        for (int j = 0; j < 4; ++j) {
            const int node = node0 + g * 4 + j;
            if (node < n_nodes) {
                #pragma unroll
                for (int nt = 0; nt < 4; ++nt) {
                    h[(size_t)node * OUT_C + nt * 16 + m] =
                        (unsigned short)f2bf(acc[nt][j]);
                }
            }
        }
    } else {
        // rowptr: 4 edges per thread (n_edges % 4 == 0 in this problem;
        // guarded anyway)
        const int t  = ((int)blockIdx.x - gemm_blocks) * 256 + threadIdx.x;
        const int e0 = t * 4;
        if (e0 >= n_edges) return;
        const int4 r4 = *(const int4*)(row + e0);
        int rprev = (e0 == 0) ? -1 : row[e0 - 1];
        int rr[4] = {r4.x, r4.y, r4.z, r4.w};
        #pragma unroll
        for (int i = 0; i < 4; ++i) {
            if (e0 + i < n_edges) {
                for (int n = rprev + 1; n <= rr[i]; ++n) rowptr[n] = e0 + i;
                rprev = rr[i];
            }
        }
        if (e0 + 4 >= n_edges) {   // last thread: close out the tail
            for (int n = rprev + 1; n <= n_nodes; ++n) rowptr[n] = n_edges;
        }
    }
}

// -------- Kernel 2: bf16 segment-sum + degree scale + bias --------
// 8 lanes per node (lane owns 8 bf16 channels = one uint4 of the h row),
// 8 nodes per wave, 32 nodes per 256-thread block. No cross-lane reduce.
// Unroll-8 with clamped edge indices: 8 independent col loads then 8
// independent 16 B gathers in flight per lane (deg~16 -> 2 iterations).
#define UNPACK_ADD(v)                                   \
    do {                                                \
        acc[0] += __uint_as_float((v).x << 16);         \
        acc[1] += __uint_as_float((v).x & 0xFFFF0000u); \
        acc[2] += __uint_as_float((v).y << 16);         \
        acc[3] += __uint_as_float((v).y & 0xFFFF0000u); \
        acc[4] += __uint_as_float((v).z << 16);         \
        acc[5] += __uint_as_float((v).z & 0xFFFF0000u); \
        acc[6] += __uint_as_float((v).w << 16);         \
        acc[7] += __uint_as_float((v).w & 0xFFFF0000u); \
    } while (0)

__global__ __launch_bounds__(256) void gcn_agg_kernel(
    const uint4* __restrict__ h4, const int* __restrict__ col,
    const int* __restrict__ rowptr, const float* __restrict__ deg,
    const float4* __restrict__ bias4, float4* __restrict__ out4,
    int n_nodes) {
    const int tid  = threadIdx.x;
    const int node = blockIdx.x * 32 + (tid >> 3);   // 8 lanes per node
    if (node >= n_nodes) return;
    const int lo   = tid & 7;                        // channel octet

    const int begin = rowptr[node];
    const int end   = rowptr[node + 1];
    const int last  = end - 1;

    float acc[8] = {0.f, 0.f, 0.f, 0.f, 0.f, 0.f, 0.f, 0.f};
    for (int e = begin; e < end; e += 8) {
        int c[8];
        #pragma unroll
        for (int i = 0; i < 8; ++i) c[i] = col[min(e + i, last)];
        uint4 v[8];
        #pragma unroll
        for (int i = 0; i < 8; ++i) v[i] = h4[(size_t)c[i] * 8 + lo];
        UNPACK_ADD(v[0]);
        #pragma unroll
        for (int i = 1; i < 8; ++i) {
            if (e + i <= last) UNPACK_ADD(v[i]);
        }
    }

    const float  d  = deg[node];
    const float4 b0 = bias4[lo * 2];
    const float4 b1 = bias4[lo * 2 + 1];
    float4 oa, ob;
    oa.x = fmaf(acc[0], d, b0.x);
    oa.y = fmaf(acc[1], d, b0.y);
    oa.z = fmaf(acc[2], d, b0.z);
    oa.w = fmaf(acc[3], d, b0.w);
    ob.x = fmaf(acc[4], d, b1.x);
    ob.y = fmaf(acc[5], d, b1.y);
    ob.z = fmaf(acc[6], d, b1.z);
    ob.w = fmaf(acc[7], d, b1.w);
    out4[(size_t)node * 16 + lo * 2]     = oa;
    out4[(size_t)node * 16 + lo * 2 + 1] = ob;
}

extern "C" void kernel_launch(void* const* d_in, const int* in_sizes, int n_in,
                              void* d_out, int out_size, void* d_ws, size_t ws_size,
                              hipStream_t stream) {
    const float* x    = (const float*)d_in[0];
    const float* w    = (const float*)d_in[1];
    const float* bias = (const float*)d_in[2];
    const int* col    = (const int*)d_in[3];
    const int* row    = (const int*)d_in[4];
    const float* deg  = (const float*)d_in[5];

    const int n_nodes = in_sizes[5];     // degrees: [N_NODES]
    const int n_edges = in_sizes[3];     // column_index: [N_EDGES]

    unsigned short* h = (unsigned short*)d_ws;            // N*64 bf16 = 12.8 MB
    int* rowptr = (int*)((char*)d_ws +
                         (size_t)n_nodes * OUT_C * sizeof(unsigned short));

    const int gemm_blocks   = (n_nodes + 63) / 64;        // 64 nodes/block
    const int rowptr_blocks = (n_edges + 1023) / 1024;    // 4 edges/thread
    gcn_prep_kernel<<<gemm_blocks + rowptr_blocks, 256, 0, stream>>>(
        x, w, h, row, rowptr, n_nodes, n_edges, gemm_blocks);

    const int agg_blocks = (n_nodes + 31) / 32;           // 32 nodes per block
    gcn_agg_kernel<<<agg_blocks, 256, 0, stream>>>(
        (const uint4*)h, col, rowptr, deg,
        (const float4*)bias, (float4*)d_out, n_nodes);
}